// Round 6
// baseline (290.051 us; speedup 1.0000x reference)
//
#include <hip/hip_runtime.h>
#include <hip/hip_bf16.h>

typedef short bf16x8 __attribute__((ext_vector_type(8)));
typedef float f32x4  __attribute__((ext_vector_type(4)));

__device__ __forceinline__ unsigned cvt2(float a, float b) {
  __hip_bfloat162 h = __float22bfloat162_rn(make_float2(a, b));
  unsigned u; __builtin_memcpy(&u, &h, 4); return u;
}

__device__ __forceinline__ f32x4 MFMA(bf16x8 a, bf16x8 b, f32x4 c) {
  return __builtin_amdgcn_mfma_f32_16x16x32_bf16(a, b, c, 0, 0, 0);
}

// XP: [128 cols][64 h] f32, XOR swizzle at 4-word (16B) granule keyed on n&15
__device__ __forceinline__ int xp_idx(int n, int h) { return (n << 6) + (h ^ ((n & 15) << 2)); }

// ---- weight permute + bf16 cast; ALL layers -> [o][m*64+h], K=2560 ----
// L0 (H=40) zero-padded to H=64: W'[o][m*64+h] = w0[o][h*40+m] if h<40 else 0
__global__ __launch_bounds__(256) void permute_w_kernel(
    const float* __restrict__ w0, const float* __restrict__ w1,
    const float* __restrict__ w2, unsigned short* __restrict__ Wp) {
  __shared__ float rowt[40 * 65];   // [m][h], padded stride 65
  const int b = blockIdx.x;
  const float* src; unsigned short* dst; int Kin, L0;
  if (b < 128)      { src = w0 + b * 1600;            dst = Wp + (size_t)b * 2560;            Kin = 1600; L0 = 1; }
  else if (b < 256) { int o = b - 128; src = w1 + o * 2560; dst = Wp + 327680 + (size_t)o * 2560; Kin = 2560; L0 = 0; }
  else              { int o = b - 256; src = w2 + o * 2560; dst = Wp + 655360 + (size_t)o * 2560; Kin = 2560; L0 = 0; }
  for (int i = threadIdx.x; i < (Kin >> 2); i += 256) {
    float4 v = ((const float4*)src)[i];
    int f = i << 2;
    int h = f / 40, m = f - h * 40;   // src h-major, m inner; 4 | 40 so no straddle
    rowt[(m + 0) * 65 + h] = v.x;
    rowt[(m + 1) * 65 + h] = v.y;
    rowt[(m + 2) * 65 + h] = v.z;
    rowt[(m + 3) * 65 + h] = v.w;
  }
  __syncthreads();
  for (int i = threadIdx.x; i < 320; i += 256) {
    const int k = i << 3;
    const int m = k >> 6, h = k & 63;
    if (L0 && h >= 40) {
      *(uint4*)&dst[k] = make_uint4(0u, 0u, 0u, 0u);
    } else {
      const float* p = &rowt[m * 65 + h];
      uint4 u;
      u.x = cvt2(p[0], p[1]); u.y = cvt2(p[2], p[3]);
      u.z = cvt2(p[4], p[5]); u.w = cvt2(p[6], p[7]);
      *(uint4*)&dst[k] = u;
    }
  }
}

// ---- fused CIN: 128 cols/block, 8 waves = 4 n-quads x 2 k-halves, o=128/wave ----
__global__ __launch_bounds__(512, 2) void cin_kernel(
    const float* __restrict__ x, const unsigned short* __restrict__ Wp,
    const float* __restrict__ bias0, const float* __restrict__ bias1,
    const float* __restrict__ bias2, const float* __restrict__ wl,
    float* __restrict__ out) {
  __shared__ __align__(16) float XP_s[128 * 64];   // 32KB: X-padded (L0), then P
  __shared__ __align__(16) float XT_s[40 * 128];   // 20KB: X transposed [m][col]
  __shared__ __align__(16) float scr_s[4 * 4096];  // 64KB: khalf-reduction scratch
  __shared__ float wl_s[192];
  __shared__ float s_s[128];

  const int tid = threadIdx.x;
  const int lane = tid & 63;
  const int wv = tid >> 6;
  const int bid = blockIdx.x;

  if (tid < 192) wl_s[tid] = wl[tid];

  {  // stage x: 8 b's, global layout (b_l, m, d)
    const float4* xg = (const float4*)(x + (size_t)bid * 5120);
    for (int i = tid; i < 1280; i += 512) {
      float4 v = xg[i];
      int d4 = (i & 3) << 2;
      int m = (i >> 2) % 40;
      int b_l = i / 160;
      int nb = b_l * 16 + d4;
      XP_s[xp_idx(nb + 0, m)] = v.x;
      XP_s[xp_idx(nb + 1, m)] = v.y;
      XP_s[xp_idx(nb + 2, m)] = v.z;
      XP_s[xp_idx(nb + 3, m)] = v.w;
      *(float4*)&XT_s[(m << 7) + nb] = v;
    }
    for (int i = tid; i < 768; i += 512) {   // zero-pad h = 40..63
      int n = i / 6, hg = 40 + (i - n * 6) * 4;
      *(float4*)&XP_s[xp_idx(n, hg)] = make_float4(0.f, 0.f, 0.f, 0.f);
    }
  }

  const int nlo = lane & 15;
  const int q = lane >> 4;
  const int orow = q << 2;
  const int swn = nlo << 2;
  const int khalf = wv & 1;
  const int nq = wv >> 1;
  const int n0 = nq * 32 + nlo;          // fn0 col; fn1 = n0+16
  const int kb0 = khalf * 1280;
  const int mbase = khalf * 20;
  const int hq0 = q << 3;                // sl0 octet base
  const int hq1 = 32 + (q << 3);         // sl1

  auto mkB = [&](const f32x4& lo, const f32x4& hi, float xv) -> bf16x8 {
    uint4 u;
    u.x = cvt2(lo[0] * xv, lo[1] * xv);
    u.y = cvt2(lo[2] * xv, lo[3] * xv);
    u.z = cvt2(hi[0] * xv, hi[1] * xv);
    u.w = cvt2(hi[2] * xv, hi[3] * xv);
    return __builtin_bit_cast(bf16x8, u);
  };

  float sacc[2] = {0.f, 0.f};

  __syncthreads();  // staging visible

  const float* biasL[3] = {bias0, bias1, bias2};

  for (int lidx = 0; lidx < 3; ++lidx) {
    const unsigned short* W = Wp + lidx * 327680;
    const float* bias = biasL[lidx];

    // ---- P register cache: [fn][slice][half], octet constant for whole layer
    const int rb0 = n0 << 6;
    const int rb1 = (n0 + 16) << 6;
    f32x4 Pc00a = *(const f32x4*)&XP_s[rb0 + (hq0 ^ swn)];
    f32x4 Pc00b = *(const f32x4*)&XP_s[rb0 + ((hq0 + 4) ^ swn)];
    f32x4 Pc01a = *(const f32x4*)&XP_s[rb0 + (hq1 ^ swn)];
    f32x4 Pc01b = *(const f32x4*)&XP_s[rb0 + ((hq1 + 4) ^ swn)];
    f32x4 Pc10a = *(const f32x4*)&XP_s[rb1 + (hq0 ^ swn)];
    f32x4 Pc10b = *(const f32x4*)&XP_s[rb1 + ((hq0 + 4) ^ swn)];
    f32x4 Pc11a = *(const f32x4*)&XP_s[rb1 + (hq1 ^ swn)];
    f32x4 Pc11b = *(const f32x4*)&XP_s[rb1 + ((hq1 + 4) ^ swn)];

    f32x4 acc[8][2];
#pragma unroll
    for (int a = 0; a < 8; ++a) { acc[a][0] = f32x4{0.f,0.f,0.f,0.f}; acc[a][1] = f32x4{0.f,0.f,0.f,0.f}; }

    const unsigned short* wr[8];
#pragma unroll
    for (int mr = 0; mr < 8; ++mr)
      wr[mr] = W + (size_t)(mr * 16 + nlo) * 2560 + kb0 + (q << 3);

    bf16x8 A0[8], A1[8], A2[8];
#pragma unroll
    for (int mr = 0; mr < 8; ++mr) A0[mr] = *(const bf16x8*)(wr[mr]);   // t=0 (sl0 of m0)

    for (int mi = 0; mi < 20; mi += 2) {
      const int t0 = mi << 1;
      // ======== m = mbase+mi (sl0 in A0) ========
#pragma unroll
      for (int mr = 0; mr < 8; ++mr) A1[mr] = *(const bf16x8*)(wr[mr] + (t0 + 1) * 32);
      float xv0 = XT_s[((mbase + mi) << 7) + n0];
      float xv1 = XT_s[((mbase + mi) << 7) + n0 + 16];
      bf16x8 B0 = mkB(Pc00a, Pc00b, xv0);
      bf16x8 B1 = mkB(Pc10a, Pc10b, xv1);
#pragma unroll
      for (int mr = 0; mr < 8; ++mr) A2[mr] = *(const bf16x8*)(wr[mr] + (t0 + 2) * 32);
#pragma unroll
      for (int mr = 0; mr < 8; ++mr) {
        acc[mr][0] = MFMA(A0[mr], B0, acc[mr][0]);
        acc[mr][1] = MFMA(A0[mr], B1, acc[mr][1]);
      }
      B0 = mkB(Pc01a, Pc01b, xv0);
      B1 = mkB(Pc11a, Pc11b, xv1);
#pragma unroll
      for (int mr = 0; mr < 8; ++mr) {
        acc[mr][0] = MFMA(A1[mr], B0, acc[mr][0]);
        acc[mr][1] = MFMA(A1[mr], B1, acc[mr][1]);
      }
      // ======== m = mbase+mi+1 (sl0 in A2) ========
#pragma unroll
      for (int mr = 0; mr < 8; ++mr) A1[mr] = *(const bf16x8*)(wr[mr] + (t0 + 3) * 32);
      xv0 = XT_s[((mbase + mi + 1) << 7) + n0];
      xv1 = XT_s[((mbase + mi + 1) << 7) + n0 + 16];
      B0 = mkB(Pc00a, Pc00b, xv0);
      B1 = mkB(Pc10a, Pc10b, xv1);
      const int t4 = (mi + 2 < 20) ? (t0 + 4) : 0;
#pragma unroll
      for (int mr = 0; mr < 8; ++mr) A0[mr] = *(const bf16x8*)(wr[mr] + t4 * 32);
#pragma unroll
      for (int mr = 0; mr < 8; ++mr) {
        acc[mr][0] = MFMA(A2[mr], B0, acc[mr][0]);
        acc[mr][1] = MFMA(A2[mr], B1, acc[mr][1]);
      }
      B0 = mkB(Pc01a, Pc01b, xv0);
      B1 = mkB(Pc11a, Pc11b, xv1);
#pragma unroll
      for (int mr = 0; mr < 8; ++mr) {
        acc[mr][0] = MFMA(A1[mr], B0, acc[mr][0]);
        acc[mr][1] = MFMA(A1[mr], B1, acc[mr][1]);
      }
    }

    // ---- epilogue: khalf-pair reduction; o<64 -> P, o>=64 -> direct sums
    __syncthreads();
    if (khalf == 1) {
#pragma unroll
      for (int mr = 0; mr < 8; ++mr)
#pragma unroll
        for (int fn = 0; fn < 2; ++fn)
          *(f32x4*)&scr_s[nq * 4096 + (mr * 2 + fn) * 256 + lane * 4] = acc[mr][fn];
    }
    __syncthreads();
    if (khalf == 0) {
#pragma unroll
      for (int mr = 0; mr < 8; ++mr)
#pragma unroll
        for (int fn = 0; fn < 2; ++fn)
          acc[mr][fn] += *(const f32x4*)&scr_s[nq * 4096 + (mr * 2 + fn) * 256 + lane * 4];
      if (lidx < 2) {
#pragma unroll
        for (int mr = 0; mr < 4; ++mr) {       // P half: o = 0..63
          const int o0 = mr * 16 + orow;
          float4 bv = *(const float4*)&bias[o0];
#pragma unroll
          for (int fn = 0; fn < 2; ++fn) {
            f32x4 a = acc[mr][fn];
            float4 r;
            r.x = fmaxf(a[0] + bv.x, 0.f);
            r.y = fmaxf(a[1] + bv.y, 0.f);
            r.z = fmaxf(a[2] + bv.z, 0.f);
            r.w = fmaxf(a[3] + bv.w, 0.f);
            *(float4*)&XP_s[xp_idx(n0 + fn * 16, o0)] = r;
          }
        }
      }
#pragma unroll
      for (int mr = 4; mr < 8; ++mr) {         // direct half: o = 64..127
        const int o0 = mr * 16 + orow;
        float4 bv = *(const float4*)&bias[o0];
        float4 wv4 = *(const float4*)&wl_s[lidx * 64 + (o0 - 64)];
#pragma unroll
        for (int fn = 0; fn < 2; ++fn) {
          f32x4 a = acc[mr][fn];
          sacc[fn] += fmaxf(a[0] + bv.x, 0.f) * wv4.x
                    + fmaxf(a[1] + bv.y, 0.f) * wv4.y
                    + fmaxf(a[2] + bv.z, 0.f) * wv4.z
                    + fmaxf(a[3] + bv.w, 0.f) * wv4.w;
        }
      }
    }
    __syncthreads();  // new P visible before next layer's Pc load
  }

  // ---- head: reduce q-groups; khalf0 waves own distinct columns -> plain store
#pragma unroll
  for (int fn = 0; fn < 2; ++fn) {
    float v = sacc[fn];
    v += __shfl_xor(v, 16);
    v += __shfl_xor(v, 32);
    if (khalf == 0 && lane < 16) s_s[nq * 32 + fn * 16 + lane] = v;
  }
  __syncthreads();
  if (tid < 8) {
    float s = 0.f;
#pragma unroll
    for (int d = 0; d < 16; ++d) s += s_s[tid * 16 + d];
    out[bid * 8 + tid] = s;
  }
}

extern "C" void kernel_launch(void* const* d_in, const int* in_sizes, int n_in,
                              void* d_out, int out_size, void* d_ws, size_t ws_size,
                              hipStream_t stream) {
  const float* x  = (const float*)d_in[0];
  const float* w0 = (const float*)d_in[1];
  const float* b0 = (const float*)d_in[2];
  const float* w1 = (const float*)d_in[3];
  const float* b1 = (const float*)d_in[4];
  const float* w2 = (const float*)d_in[5];
  const float* b2 = (const float*)d_in[6];
  const float* wl = (const float*)d_in[7];
  unsigned short* Wp = (unsigned short*)d_ws;  // 983040 bf16 = 1.92 MB

  permute_w_kernel<<<384, 256, 0, stream>>>(w0, w1, w2, Wp);
  cin_kernel<<<256, 512, 0, stream>>>(x, Wp, b0, b1, b2, wl, (float*)d_out);
}

// Round 7
// 289.529 us; speedup vs baseline: 1.0018x; 1.0018x over previous
//
#include <hip/hip_runtime.h>
#include <hip/hip_bf16.h>

typedef short bf16x8 __attribute__((ext_vector_type(8)));
typedef float f32x4  __attribute__((ext_vector_type(4)));

__device__ __forceinline__ unsigned cvt2(float a, float b) {
  __hip_bfloat162 h = __float22bfloat162_rn(make_float2(a, b));
  unsigned u; __builtin_memcpy(&u, &h, 4); return u;
}

__device__ __forceinline__ f32x4 MFMA(bf16x8 a, bf16x8 b, f32x4 c) {
  return __builtin_amdgcn_mfma_f32_16x16x32_bf16(a, b, c, 0, 0, 0);
}

// XP: [128 cols][64 h] f32, XOR swizzle at 4-word (16B) granule keyed on n&15
__device__ __forceinline__ int xp_idx(int n, int h) { return (n << 6) + (h ^ ((n & 15) << 2)); }

// ---- weight permute + bf16 cast; ALL layers -> [o][m*64+h], K=2560 ----
// L0 (H=40) zero-padded to H=64: W'[o][m*64+h] = w0[o][h*40+m] if h<40 else 0
__global__ __launch_bounds__(256) void permute_w_kernel(
    const float* __restrict__ w0, const float* __restrict__ w1,
    const float* __restrict__ w2, unsigned short* __restrict__ Wp) {
  __shared__ float rowt[40 * 65];   // [m][h], padded stride 65
  const int b = blockIdx.x;
  const float* src; unsigned short* dst; int Kin, L0;
  if (b < 128)      { src = w0 + b * 1600;            dst = Wp + (size_t)b * 2560;            Kin = 1600; L0 = 1; }
  else if (b < 256) { int o = b - 128; src = w1 + o * 2560; dst = Wp + 327680 + (size_t)o * 2560; Kin = 2560; L0 = 0; }
  else              { int o = b - 256; src = w2 + o * 2560; dst = Wp + 655360 + (size_t)o * 2560; Kin = 2560; L0 = 0; }
  for (int i = threadIdx.x; i < (Kin >> 2); i += 256) {
    float4 v = ((const float4*)src)[i];
    int f = i << 2;
    int h = f / 40, m = f - h * 40;   // src h-major, m inner; 4 | 40 so no straddle
    rowt[(m + 0) * 65 + h] = v.x;
    rowt[(m + 1) * 65 + h] = v.y;
    rowt[(m + 2) * 65 + h] = v.z;
    rowt[(m + 3) * 65 + h] = v.w;
  }
  __syncthreads();
  for (int i = threadIdx.x; i < 320; i += 256) {
    const int k = i << 3;
    const int m = k >> 6, h = k & 63;
    if (L0 && h >= 40) {
      *(uint4*)&dst[k] = make_uint4(0u, 0u, 0u, 0u);
    } else {
      const float* p = &rowt[m * 65 + h];
      uint4 u;
      u.x = cvt2(p[0], p[1]); u.y = cvt2(p[2], p[3]);
      u.z = cvt2(p[4], p[5]); u.w = cvt2(p[6], p[7]);
      *(uint4*)&dst[k] = u;
    }
  }
}

// ---- fused CIN: 128 cols/block, 16 waves = 4 nq x 2 khalf x 2 ohalf ----
// o=64/wave (4 mr), n=32/wave (2 fn), K/2 per wave. 1024-thread block -> 4 waves/SIMD.
__global__ __launch_bounds__(1024, 4) void cin_kernel(
    const float* __restrict__ x, const unsigned short* __restrict__ Wp,
    const float* __restrict__ bias0, const float* __restrict__ bias1,
    const float* __restrict__ bias2, const float* __restrict__ wl,
    float* __restrict__ out) {
  __shared__ __align__(16) float XP_s[128 * 64];   // 32KB: X-padded (L0), then P
  __shared__ __align__(16) float XT_s[40 * 128];   // 20KB: X transposed [m][col]
  __shared__ __align__(16) float scr_s[16384];     // 64KB: khalf-reduction scratch
  __shared__ float wl_s[192];
  __shared__ float s_s[128];

  const int tid = threadIdx.x;
  const int lane = tid & 63;
  const int wv = tid >> 6;          // 0..15
  const int bid = blockIdx.x;

  if (tid < 192) wl_s[tid] = wl[tid];

  {  // stage x: 8 b's, global layout (b_l, m, d)
    const float4* xg = (const float4*)(x + (size_t)bid * 5120);
    for (int i = tid; i < 1280; i += 1024) {
      float4 v = xg[i];
      int d4 = (i & 3) << 2;
      int m = (i >> 2) % 40;
      int b_l = i / 160;
      int nb = b_l * 16 + d4;
      XP_s[xp_idx(nb + 0, m)] = v.x;
      XP_s[xp_idx(nb + 1, m)] = v.y;
      XP_s[xp_idx(nb + 2, m)] = v.z;
      XP_s[xp_idx(nb + 3, m)] = v.w;
      *(float4*)&XT_s[(m << 7) + nb] = v;
    }
    if (tid < 768) {                 // zero-pad h = 40..63
      int n = tid / 6, hg = 40 + (tid - n * 6) * 4;
      *(float4*)&XP_s[xp_idx(n, hg)] = make_float4(0.f, 0.f, 0.f, 0.f);
    }
  }

  const int nlo = lane & 15;
  const int q = lane >> 4;
  const int orow = q << 2;
  const int swn = nlo << 2;
  const int khalf = wv & 1;
  const int ohalf = (wv >> 1) & 1;
  const int nq = wv >> 2;                // 0..3
  const int n0 = nq * 32 + nlo;          // fn0 col; fn1 = n0+16
  const int obase = ohalf << 6;          // wave's o-range: 64 rows
  const int kb0 = khalf * 1280;
  const int mbase = khalf * 20;
  const int hq0 = q << 3;                // sl0 octet base
  const int hq1 = 32 + (q << 3);         // sl1

  auto mkB = [&](const f32x4& lo, const f32x4& hi, float xv) -> bf16x8 {
    uint4 u;
    u.x = cvt2(lo[0] * xv, lo[1] * xv);
    u.y = cvt2(lo[2] * xv, lo[3] * xv);
    u.z = cvt2(hi[0] * xv, hi[1] * xv);
    u.w = cvt2(hi[2] * xv, hi[3] * xv);
    return __builtin_bit_cast(bf16x8, u);
  };

  float sacc[2] = {0.f, 0.f};

  __syncthreads();  // staging visible

  const float* biasL[3] = {bias0, bias1, bias2};

  for (int lidx = 0; lidx < 3; ++lidx) {
    const unsigned short* W = Wp + lidx * 327680;
    const float* bias = biasL[lidx];

    // ---- P register cache: octet constant for the whole layer (8 f32x4)
    const int rb0 = n0 << 6;
    const int rb1 = (n0 + 16) << 6;
    f32x4 Pc00a = *(const f32x4*)&XP_s[rb0 + (hq0 ^ swn)];
    f32x4 Pc00b = *(const f32x4*)&XP_s[rb0 + ((hq0 + 4) ^ swn)];
    f32x4 Pc01a = *(const f32x4*)&XP_s[rb0 + (hq1 ^ swn)];
    f32x4 Pc01b = *(const f32x4*)&XP_s[rb0 + ((hq1 + 4) ^ swn)];
    f32x4 Pc10a = *(const f32x4*)&XP_s[rb1 + (hq0 ^ swn)];
    f32x4 Pc10b = *(const f32x4*)&XP_s[rb1 + ((hq0 + 4) ^ swn)];
    f32x4 Pc11a = *(const f32x4*)&XP_s[rb1 + (hq1 ^ swn)];
    f32x4 Pc11b = *(const f32x4*)&XP_s[rb1 + ((hq1 + 4) ^ swn)];

    f32x4 acc[4][2];
#pragma unroll
    for (int a = 0; a < 4; ++a) { acc[a][0] = f32x4{0.f,0.f,0.f,0.f}; acc[a][1] = f32x4{0.f,0.f,0.f,0.f}; }

    const unsigned short* wr[4];
#pragma unroll
    for (int mr = 0; mr < 4; ++mr)
      wr[mr] = W + (size_t)(obase + mr * 16 + nlo) * 2560 + kb0 + (q << 3);

    bf16x8 A0[4], A1[4], A2[4];
#pragma unroll
    for (int mr = 0; mr < 4; ++mr) A0[mr] = *(const bf16x8*)(wr[mr]);   // t=0 (sl0 of m0)

    for (int mi = 0; mi < 20; mi += 2) {
      const int t0 = mi << 1;
      // ======== m = mbase+mi (sl0 in A0) ========
#pragma unroll
      for (int mr = 0; mr < 4; ++mr) A1[mr] = *(const bf16x8*)(wr[mr] + (t0 + 1) * 32);
      float xv0 = XT_s[((mbase + mi) << 7) + n0];
      float xv1 = XT_s[((mbase + mi) << 7) + n0 + 16];
      bf16x8 B0 = mkB(Pc00a, Pc00b, xv0);
      bf16x8 B1 = mkB(Pc10a, Pc10b, xv1);
#pragma unroll
      for (int mr = 0; mr < 4; ++mr) A2[mr] = *(const bf16x8*)(wr[mr] + (t0 + 2) * 32);
#pragma unroll
      for (int mr = 0; mr < 4; ++mr) {
        acc[mr][0] = MFMA(A0[mr], B0, acc[mr][0]);
        acc[mr][1] = MFMA(A0[mr], B1, acc[mr][1]);
      }
      B0 = mkB(Pc01a, Pc01b, xv0);
      B1 = mkB(Pc11a, Pc11b, xv1);
#pragma unroll
      for (int mr = 0; mr < 4; ++mr) {
        acc[mr][0] = MFMA(A1[mr], B0, acc[mr][0]);
        acc[mr][1] = MFMA(A1[mr], B1, acc[mr][1]);
      }
      // ======== m = mbase+mi+1 (sl0 in A2) ========
#pragma unroll
      for (int mr = 0; mr < 4; ++mr) A1[mr] = *(const bf16x8*)(wr[mr] + (t0 + 3) * 32);
      xv0 = XT_s[((mbase + mi + 1) << 7) + n0];
      xv1 = XT_s[((mbase + mi + 1) << 7) + n0 + 16];
      B0 = mkB(Pc00a, Pc00b, xv0);
      B1 = mkB(Pc10a, Pc10b, xv1);
      const int t4 = (mi + 2 < 20) ? (t0 + 4) : 0;
#pragma unroll
      for (int mr = 0; mr < 4; ++mr) A0[mr] = *(const bf16x8*)(wr[mr] + t4 * 32);
#pragma unroll
      for (int mr = 0; mr < 4; ++mr) {
        acc[mr][0] = MFMA(A2[mr], B0, acc[mr][0]);
        acc[mr][1] = MFMA(A2[mr], B1, acc[mr][1]);
      }
      B0 = mkB(Pc01a, Pc01b, xv0);
      B1 = mkB(Pc11a, Pc11b, xv1);
#pragma unroll
      for (int mr = 0; mr < 4; ++mr) {
        acc[mr][0] = MFMA(A1[mr], B0, acc[mr][0]);
        acc[mr][1] = MFMA(A1[mr], B1, acc[mr][1]);
      }
    }

    // ---- epilogue: khalf-pair reduction (one 64KB round); o<64 -> P, o>=64 -> sacc
    const int wslot = (nq << 1) | ohalf;   // 0..7
    __syncthreads();
    if (khalf == 1) {
#pragma unroll
      for (int mr = 0; mr < 4; ++mr)
#pragma unroll
        for (int fn = 0; fn < 2; ++fn)
          *(f32x4*)&scr_s[wslot * 2048 + (mr * 2 + fn) * 256 + lane * 4] = acc[mr][fn];
    }
    __syncthreads();
    if (khalf == 0) {
#pragma unroll
      for (int mr = 0; mr < 4; ++mr)
#pragma unroll
        for (int fn = 0; fn < 2; ++fn)
          acc[mr][fn] += *(const f32x4*)&scr_s[wslot * 2048 + (mr * 2 + fn) * 256 + lane * 4];
      if (ohalf == 0) {
        if (lidx < 2) {
#pragma unroll
          for (int mr = 0; mr < 4; ++mr) {       // P half: o = 0..63
            const int o0 = mr * 16 + orow;
            float4 bv = *(const float4*)&bias[o0];
#pragma unroll
            for (int fn = 0; fn < 2; ++fn) {
              f32x4 a = acc[mr][fn];
              float4 r;
              r.x = fmaxf(a[0] + bv.x, 0.f);
              r.y = fmaxf(a[1] + bv.y, 0.f);
              r.z = fmaxf(a[2] + bv.z, 0.f);
              r.w = fmaxf(a[3] + bv.w, 0.f);
              *(float4*)&XP_s[xp_idx(n0 + fn * 16, o0)] = r;
            }
          }
        }
      } else {
#pragma unroll
        for (int mr = 0; mr < 4; ++mr) {         // direct half: o = 64..127
          const int o0 = 64 + mr * 16 + orow;
          float4 bv = *(const float4*)&bias[o0];
          float4 wv4 = *(const float4*)&wl_s[lidx * 64 + (o0 - 64)];
#pragma unroll
          for (int fn = 0; fn < 2; ++fn) {
            f32x4 a = acc[mr][fn];
            sacc[fn] += fmaxf(a[0] + bv.x, 0.f) * wv4.x
                      + fmaxf(a[1] + bv.y, 0.f) * wv4.y
                      + fmaxf(a[2] + bv.z, 0.f) * wv4.z
                      + fmaxf(a[3] + bv.w, 0.f) * wv4.w;
          }
        }
      }
    }
    __syncthreads();  // new P visible before next layer's Pc load
  }

  // ---- head: sacc lives in khalf0/ohalf1 waves; distinct columns -> plain store
#pragma unroll
  for (int fn = 0; fn < 2; ++fn) {
    float v = sacc[fn];
    v += __shfl_xor(v, 16);
    v += __shfl_xor(v, 32);
    if (khalf == 0 && ohalf == 1 && lane < 16) s_s[nq * 32 + fn * 16 + lane] = v;
  }
  __syncthreads();
  if (tid < 8) {
    float s = 0.f;
#pragma unroll
    for (int d = 0; d < 16; ++d) s += s_s[tid * 16 + d];
    out[bid * 8 + tid] = s;
  }
}

extern "C" void kernel_launch(void* const* d_in, const int* in_sizes, int n_in,
                              void* d_out, int out_size, void* d_ws, size_t ws_size,
                              hipStream_t stream) {
  const float* x  = (const float*)d_in[0];
  const float* w0 = (const float*)d_in[1];
  const float* b0 = (const float*)d_in[2];
  const float* w1 = (const float*)d_in[3];
  const float* b1 = (const float*)d_in[4];
  const float* w2 = (const float*)d_in[5];
  const float* b2 = (const float*)d_in[6];
  const float* wl = (const float*)d_in[7];
  unsigned short* Wp = (unsigned short*)d_ws;  // 983040 bf16 = 1.92 MB

  permute_w_kernel<<<384, 256, 0, stream>>>(w0, w1, w2, Wp);
  cin_kernel<<<256, 1024, 0, stream>>>(x, Wp, b0, b1, b2, wl, (float*)d_out);
}

// Round 8
// 173.432 us; speedup vs baseline: 1.6724x; 1.6694x over previous
//
#include <hip/hip_runtime.h>
#include <hip/hip_bf16.h>

typedef short bf16x8  __attribute__((ext_vector_type(8)));
typedef float f32x4   __attribute__((ext_vector_type(4)));
typedef float f32x16  __attribute__((ext_vector_type(16)));

__device__ __forceinline__ unsigned cvt2(float a, float b) {
  __hip_bfloat162 h = __float22bfloat162_rn(make_float2(a, b));
  unsigned u; __builtin_memcpy(&u, &h, 4); return u;
}

__device__ __forceinline__ f32x16 MFMA(bf16x8 a, bf16x8 b, f32x16 c) {
  return __builtin_amdgcn_mfma_f32_32x32x16_bf16(a, b, c, 0, 0, 0);
}

// XP: [64 cols][64 h] f32, XOR swizzle at 4-word (16B) granule keyed on n&15
__device__ __forceinline__ int xp_idx(int n, int h) { return (n << 6) + (h ^ ((n & 15) << 2)); }

// ---- weight permute + bf16 cast into FRAGMENT-MAJOR layout ----
// Logical W'[o][k'], k' = m*64 + h (L0 zero-padded h>=40).
// Physical: W''[ layer ][ (ot*160 + s)*64 + lane ][ e ]  (shorts), where
//   o = ot*32 + (lane&31), k' = s*16 + (lane>>5)*8 + e
// -> one 32x32x16 A-fragment = contiguous 1KB per wave.
__global__ __launch_bounds__(256) void permute_w_kernel(
    const float* __restrict__ w0, const float* __restrict__ w1,
    const float* __restrict__ w2, unsigned short* __restrict__ Wp) {
  __shared__ float rowt[40 * 65];   // [m][h], padded stride 65
  const int b = blockIdx.x;
  const float* src; unsigned short* dst; int Kin, L0, o;
  if (b < 128)      { o = b;       src = w0 + o * 1600; dst = Wp;          Kin = 1600; L0 = 1; }
  else if (b < 256) { o = b - 128; src = w1 + o * 2560; dst = Wp + 327680; Kin = 2560; L0 = 0; }
  else              { o = b - 256; src = w2 + o * 2560; dst = Wp + 655360; Kin = 2560; L0 = 0; }
  for (int i = threadIdx.x; i < (Kin >> 2); i += 256) {
    float4 v = ((const float4*)src)[i];
    int f = i << 2;
    int h = f / 40, m = f - h * 40;   // src h-major, m inner; 4 | 40 so no straddle
    rowt[(m + 0) * 65 + h] = v.x;
    rowt[(m + 1) * 65 + h] = v.y;
    rowt[(m + 2) * 65 + h] = v.z;
    rowt[(m + 3) * 65 + h] = v.w;
  }
  __syncthreads();
  const int ot = o >> 5, lanelo = o & 31;
  for (int i = threadIdx.x; i < 320; i += 256) {   // k-octets
    const int k = i << 3;
    const int m = k >> 6, h = k & 63;
    const int s = k >> 4, hi2 = (k >> 3) & 1;
    uint4 u;
    if (L0 && h >= 40) {
      u = make_uint4(0u, 0u, 0u, 0u);
    } else {
      const float* p = &rowt[m * 65 + h];
      u.x = cvt2(p[0], p[1]); u.y = cvt2(p[2], p[3]);
      u.z = cvt2(p[4], p[5]); u.w = cvt2(p[6], p[7]);
    }
    *(uint4*)&dst[(((size_t)ot * 160 + s) * 64 + lanelo + hi2 * 32) * 8] = u;
  }
}

// ---- fused CIN: 64 cols/block, 8 waves = 2 o-halves x 4 k-quarters ----
// 32x32x16 MFMA; wave: mr=2 (o=64), fn=2 (all 64 cols), slices s == ki (mod 4)
// -> lane h-octet constant per layer -> P in 16 regs; no in-loop barriers.
__global__ __launch_bounds__(512, 4) void cin_kernel(
    const float* __restrict__ x, const unsigned short* __restrict__ Wp,
    const float* __restrict__ bias0, const float* __restrict__ bias1,
    const float* __restrict__ bias2, const float* __restrict__ wl,
    float* __restrict__ out) {
  __shared__ __align__(16) float XP_s[64 * 64];   // 16KB: X-padded (L0) then P
  __shared__ __align__(16) float XT_s[40 * 64];   // 10KB: X transposed [m][col]
  __shared__ __align__(16) float scr_s[8192];     // 32KB: k-reduction scratch
  __shared__ float wl_s[192];
  __shared__ float s_s[64];

  const int tid = threadIdx.x;
  const int lane = tid & 63;
  const int wv = tid >> 6;        // 0..7
  const int bid = blockIdx.x;
  const int l31 = lane & 31;
  const int hi = lane >> 5;
  const int ki = wv & 3;          // k-quarter
  const int oi = wv >> 2;         // o-half

  if (tid < 192) wl_s[tid] = wl[tid];
  {  // stage x: 4 b's, global layout (b_l, m, d)
    const float4* xg = (const float4*)(x + (size_t)bid * 2560);
    for (int i = tid; i < 640; i += 512) {
      float4 v = xg[i];
      int d4 = (i & 3) << 2;
      int m = (i >> 2) % 40;
      int b_l = i / 160;
      int nb = b_l * 16 + d4;
      XP_s[xp_idx(nb + 0, m)] = v.x;
      XP_s[xp_idx(nb + 1, m)] = v.y;
      XP_s[xp_idx(nb + 2, m)] = v.z;
      XP_s[xp_idx(nb + 3, m)] = v.w;
      *(float4*)&XT_s[(m << 6) + nb] = v;
    }
    if (tid < 384) {   // zero-pad h = 40..63 (L0's P = X)
      int n = tid / 6, hg = 40 + (tid - n * 6) * 4;
      *(float4*)&XP_s[xp_idx(n, hg)] = make_float4(0.f, 0.f, 0.f, 0.f);
    }
  }
  __syncthreads();

  const int hq = ki * 16 + hi * 8;   // lane's layer-constant h-octet base
  float sacc[2] = {0.f, 0.f};
  const float* biasL[3] = {bias0, bias1, bias2};

  auto mkB = [&](const f32x4& lo, const f32x4& hi4, float xv) -> bf16x8 {
    f32x4 a = lo * xv;          // v_pk_mul_f32
    f32x4 c = hi4 * xv;
    uint4 u;
    u.x = cvt2(a[0], a[1]); u.y = cvt2(a[2], a[3]);
    u.z = cvt2(c[0], c[1]); u.w = cvt2(c[2], c[3]);
    return __builtin_bit_cast(bf16x8, u);
  };

  for (int lidx = 0; lidx < 3; ++lidx) {
    const unsigned short* W = Wp + (size_t)lidx * 327680;
    const float* bias = biasL[lidx];

    f32x16 acc[2][2];
#pragma unroll
    for (int a = 0; a < 2; ++a)
#pragma unroll
      for (int c = 0; c < 2; ++c)
#pragma unroll
        for (int e = 0; e < 16; ++e) acc[a][c][e] = 0.f;

    if (!(lidx == 0 && ki == 3)) {   // ki=3 is pure zero-pad for L0
      // P register cache: octet [hq..hq+7] for both fn cols, layer-constant
      const int col0 = l31, col1 = 32 + l31;
      const int sw0 = (col0 & 15) << 2, sw1 = (col1 & 15) << 2;
      f32x4 P0a = *(const f32x4*)&XP_s[(col0 << 6) + (hq ^ sw0)];
      f32x4 P0b = *(const f32x4*)&XP_s[(col0 << 6) + ((hq + 4) ^ sw0)];
      f32x4 P1a = *(const f32x4*)&XP_s[(col1 << 6) + (hq ^ sw1)];
      f32x4 P1b = *(const f32x4*)&XP_s[(col1 << 6) + ((hq + 4) ^ sw1)];

      // fragment streams: slice s = 4t + ki, per-t stride = 4*512 = 2048 shorts
      const unsigned short* w0p = W + (((size_t)(oi * 2 + 0) * 160 + ki) << 9) + (lane << 3);
      const unsigned short* w1p = W + (((size_t)(oi * 2 + 1) * 160 + ki) << 9) + (lane << 3);

      bf16x8 Aa0 = *(const bf16x8*)w0p;
      bf16x8 Aa1 = *(const bf16x8*)w1p;
      bf16x8 Ab0, Ab1;
      for (int t = 0; t < 40; t += 2) {
        Ab0 = *(const bf16x8*)(w0p + (t + 1) * 2048);
        Ab1 = *(const bf16x8*)(w1p + (t + 1) * 2048);
        float xv0 = XT_s[(t << 6) + l31];
        float xv1 = XT_s[(t << 6) + 32 + l31];
        bf16x8 B0 = mkB(P0a, P0b, xv0);
        bf16x8 B1 = mkB(P1a, P1b, xv1);
        acc[0][0] = MFMA(Aa0, B0, acc[0][0]);
        acc[0][1] = MFMA(Aa0, B1, acc[0][1]);
        acc[1][0] = MFMA(Aa1, B0, acc[1][0]);
        acc[1][1] = MFMA(Aa1, B1, acc[1][1]);
        const int t2 = (t + 2 < 40) ? t + 2 : 0;
        Aa0 = *(const bf16x8*)(w0p + t2 * 2048);
        Aa1 = *(const bf16x8*)(w1p + t2 * 2048);
        xv0 = XT_s[((t + 1) << 6) + l31];
        xv1 = XT_s[((t + 1) << 6) + 32 + l31];
        B0 = mkB(P0a, P0b, xv0);
        B1 = mkB(P1a, P1b, xv1);
        acc[0][0] = MFMA(Ab0, B0, acc[0][0]);
        acc[0][1] = MFMA(Ab0, B1, acc[0][1]);
        acc[1][0] = MFMA(Ab1, B0, acc[1][0]);
        acc[1][1] = MFMA(Ab1, B1, acc[1][1]);
      }
    }

    // ---- k-reduction tree: (ki 2,3 -> 0,1) in two mr sub-rounds, then ki 1 -> 0
    __syncthreads();
#pragma unroll
    for (int mr = 0; mr < 2; ++mr) {
      if (ki >= 2) {
        const int base = ((oi << 1) | (ki - 2)) * 2048;
#pragma unroll
        for (int f = 0; f < 2; ++f)
#pragma unroll
          for (int qd = 0; qd < 4; ++qd) {
            f32x4 v = {acc[mr][f][qd*4+0], acc[mr][f][qd*4+1], acc[mr][f][qd*4+2], acc[mr][f][qd*4+3]};
            *(f32x4*)&scr_s[base + (f * 4 + qd) * 256 + (lane << 2)] = v;
          }
      }
      __syncthreads();
      if (ki < 2) {
        const int base = ((oi << 1) | ki) * 2048;
#pragma unroll
        for (int f = 0; f < 2; ++f)
#pragma unroll
          for (int qd = 0; qd < 4; ++qd) {
            f32x4 v = *(const f32x4*)&scr_s[base + (f * 4 + qd) * 256 + (lane << 2)];
#pragma unroll
            for (int r = 0; r < 4; ++r) acc[mr][f][qd * 4 + r] += v[r];
          }
      }
      __syncthreads();
    }
    if (ki == 1) {
      const int base = oi * 4096;
#pragma unroll
      for (int mr = 0; mr < 2; ++mr)
#pragma unroll
        for (int f = 0; f < 2; ++f)
#pragma unroll
          for (int qd = 0; qd < 4; ++qd) {
            f32x4 v = {acc[mr][f][qd*4+0], acc[mr][f][qd*4+1], acc[mr][f][qd*4+2], acc[mr][f][qd*4+3]};
            *(f32x4*)&scr_s[base + ((mr * 2 + f) * 4 + qd) * 256 + (lane << 2)] = v;
          }
    }
    __syncthreads();
    if (ki == 0) {
      const int base = oi * 4096;
#pragma unroll
      for (int mr = 0; mr < 2; ++mr)
#pragma unroll
        for (int f = 0; f < 2; ++f)
#pragma unroll
          for (int qd = 0; qd < 4; ++qd) {
            f32x4 v = *(const f32x4*)&scr_s[base + ((mr * 2 + f) * 4 + qd) * 256 + (lane << 2)];
#pragma unroll
            for (int r = 0; r < 4; ++r) acc[mr][f][qd * 4 + r] += v[r];
          }
      if (oi == 0) {       // P half: o = 0..63 -> next layer's P
        if (lidx < 2) {
#pragma unroll
          for (int mr = 0; mr < 2; ++mr)
#pragma unroll
            for (int f = 0; f < 2; ++f) {
              const int col = f * 32 + l31;
              const int rb = col << 6, sw = (col & 15) << 2;
#pragma unroll
              for (int qd = 0; qd < 4; ++qd) {
                const int o0 = mr * 32 + qd * 8 + hi * 4;
                float4 bv = *(const float4*)&bias[o0];
                f32x4 r;
                r[0] = fmaxf(acc[mr][f][qd*4+0] + bv.x, 0.f);
                r[1] = fmaxf(acc[mr][f][qd*4+1] + bv.y, 0.f);
                r[2] = fmaxf(acc[mr][f][qd*4+2] + bv.z, 0.f);
                r[3] = fmaxf(acc[mr][f][qd*4+3] + bv.w, 0.f);
                *(f32x4*)&XP_s[rb + (o0 ^ sw)] = r;
              }
            }
        }
      } else {             // direct half: o = 64..127 -> fold with wl
#pragma unroll
        for (int mr = 0; mr < 2; ++mr)
#pragma unroll
          for (int f = 0; f < 2; ++f)
#pragma unroll
            for (int qd = 0; qd < 4; ++qd) {
              const int o0 = 64 + mr * 32 + qd * 8 + hi * 4;
              float4 bv = *(const float4*)&bias[o0];
              float4 wv4 = *(const float4*)&wl_s[lidx * 64 + (o0 - 64)];
              sacc[f] += fmaxf(acc[mr][f][qd*4+0] + bv.x, 0.f) * wv4.x
                       + fmaxf(acc[mr][f][qd*4+1] + bv.y, 0.f) * wv4.y
                       + fmaxf(acc[mr][f][qd*4+2] + bv.z, 0.f) * wv4.z
                       + fmaxf(acc[mr][f][qd*4+3] + bv.w, 0.f) * wv4.w;
            }
      }
    }
    __syncthreads();   // new P visible before next layer's Pc load
  }

  // ---- head: only wave (oi=1, ki=0) holds direct partials
  sacc[0] += __shfl_xor(sacc[0], 32);
  sacc[1] += __shfl_xor(sacc[1], 32);
  if (oi == 1 && ki == 0 && lane < 32) {
    s_s[l31] = sacc[0];
    s_s[32 + l31] = sacc[1];
  }
  __syncthreads();
  if (tid < 4) {
    float s = 0.f;
#pragma unroll
    for (int d = 0; d < 16; ++d) s += s_s[tid * 16 + d];
    out[bid * 4 + tid] = s;
  }
}

extern "C" void kernel_launch(void* const* d_in, const int* in_sizes, int n_in,
                              void* d_out, int out_size, void* d_ws, size_t ws_size,
                              hipStream_t stream) {
  const float* x  = (const float*)d_in[0];
  const float* w0 = (const float*)d_in[1];
  const float* b0 = (const float*)d_in[2];
  const float* w1 = (const float*)d_in[3];
  const float* b1 = (const float*)d_in[4];
  const float* w2 = (const float*)d_in[5];
  const float* b2 = (const float*)d_in[6];
  const float* wl = (const float*)d_in[7];
  unsigned short* Wp = (unsigned short*)d_ws;  // 983040 bf16 = 1.92 MB

  permute_w_kernel<<<384, 256, 0, stream>>>(w0, w1, w2, Wp);
  cin_kernel<<<512, 512, 0, stream>>>(x, Wp, b0, b1, b2, wl, (float*)d_out);
}

// Round 10
// 137.042 us; speedup vs baseline: 2.1165x; 1.2655x over previous
//
#include <hip/hip_runtime.h>
#include <hip/hip_bf16.h>

typedef _Float16 f16x8 __attribute__((ext_vector_type(8)));
typedef float f32x4   __attribute__((ext_vector_type(4)));
typedef float f32x16  __attribute__((ext_vector_type(16)));

__device__ __forceinline__ unsigned cvt2h(float a, float b) {
  auto h = __builtin_amdgcn_cvt_pkrtz(a, b);   // __fp16 ext_vector(2)
  unsigned u; __builtin_memcpy(&u, &h, 4); return u;
}

__device__ __forceinline__ f32x16 MFMA(uint4 a, uint4 b, f32x16 c) {
  return __builtin_amdgcn_mfma_f32_32x32x16_f16(
      __builtin_bit_cast(f16x8, a), __builtin_bit_cast(f16x8, b), c, 0, 0, 0);
}

// XP: [128 cols][64 h] f32, XOR swizzle at 4-word (16B) granule keyed on n&15
__device__ __forceinline__ int xp_idx(int n, int h) { return (n << 6) + (h ^ ((n & 15) << 2)); }

// ---- weight permute + fp16 cast into FRAGMENT-MAJOR layout ----
// Logical W'[o][k'], k' = m*64 + h (L0 zero-padded h>=40).
// Physical halves: W''[(ot*160 + s)*64 + fl]*8 + e, fl = (o&31) + ((k&15)>>3)*32
// -> one 32x32x16 A-fragment = contiguous 1KB per wave.
__global__ __launch_bounds__(256) void permute_w_kernel(
    const float* __restrict__ w0, const float* __restrict__ w1,
    const float* __restrict__ w2, unsigned short* __restrict__ Wp) {
  __shared__ float rowt[40 * 65];   // [m][h], padded stride 65
  const int b = blockIdx.x;
  const float* src; unsigned short* dst; int Kin, L0, o;
  if (b < 128)      { o = b;       src = w0 + o * 1600; dst = Wp;          Kin = 1600; L0 = 1; }
  else if (b < 256) { o = b - 128; src = w1 + o * 2560; dst = Wp + 327680; Kin = 2560; L0 = 0; }
  else              { o = b - 256; src = w2 + o * 2560; dst = Wp + 655360; Kin = 2560; L0 = 0; }
  for (int i = threadIdx.x; i < (Kin >> 2); i += 256) {
    float4 v = ((const float4*)src)[i];
    int f = i << 2;
    int h = f / 40, m = f - h * 40;   // src h-major, m inner; 4 | 40 so no straddle
    rowt[(m + 0) * 65 + h] = v.x;
    rowt[(m + 1) * 65 + h] = v.y;
    rowt[(m + 2) * 65 + h] = v.z;
    rowt[(m + 3) * 65 + h] = v.w;
  }
  __syncthreads();
  const int ot = o >> 5, lanelo = o & 31;
  for (int i = threadIdx.x; i < 320; i += 256) {   // k-octets
    const int k = i << 3;
    const int m = k >> 6, h = k & 63;
    const int s = k >> 4, hi2 = (k >> 3) & 1;
    uint4 u;
    if (L0 && h >= 40) {
      u = make_uint4(0u, 0u, 0u, 0u);
    } else {
      const float* p = &rowt[m * 65 + h];
      u.x = cvt2h(p[0], p[1]); u.y = cvt2h(p[2], p[3]);
      u.z = cvt2h(p[4], p[5]); u.w = cvt2h(p[6], p[7]);
    }
    *(uint4*)&dst[(((size_t)ot * 160 + s) * 64 + lanelo + hi2 * 32) * 8] = u;
  }
}

// ---- fused CIN: 128 cols/block, 16 waves = 4 oq x 4 ki ----
// 32x32x16 f16 MFMA; wave: mr=1 (o=32), fn=4 (128 cols), slices s == ki (mod 4)
// -> lane h-octet constant per layer -> P packed fp16 in 16 regs; no in-loop barriers.
__global__ __launch_bounds__(1024, 1) void cin_kernel(
    const float* __restrict__ x, const unsigned short* __restrict__ Wp,
    const float* __restrict__ bias0, const float* __restrict__ bias1,
    const float* __restrict__ bias2, const float* __restrict__ wl,
    float* __restrict__ out) {
  __shared__ __align__(16) float XP_s[128 * 64];     // 32KB: X-padded (L0) then P
  __shared__ __align__(16) unsigned XT_u[40 * 128];  // 20KB: x as dup'd fp16 pairs [m][col]
  __shared__ __align__(16) float scr_s[16384];       // 64KB: k-reduction scratch
  __shared__ float wl_s[192];
  __shared__ float s_s[128];

  const int tid = threadIdx.x;
  const int lane = tid & 63;
  const int wv = tid >> 6;        // 0..15
  const int bid = blockIdx.x;
  const int l31 = lane & 31;
  const int hi = lane >> 5;
  const int ki = wv & 3;          // k-stripe (s mod 4)
  const int oq = wv >> 2;         // o-quarter (32 rows)

  if (tid < 192) wl_s[tid] = wl[tid];
  if (tid < 128) s_s[tid] = 0.f;

  {  // stage x: 8 b's, global layout (b_l, m, d)
    const float4* xg = (const float4*)(x + (size_t)bid * 5120);
    for (int i = tid; i < 1280; i += 1024) {
      float4 v = xg[i];
      int d4 = (i & 3) << 2;
      int m = (i >> 2) % 40;
      int b_l = i / 160;
      int nb = b_l * 16 + d4;
      XP_s[xp_idx(nb + 0, m)] = v.x;
      XP_s[xp_idx(nb + 1, m)] = v.y;
      XP_s[xp_idx(nb + 2, m)] = v.z;
      XP_s[xp_idx(nb + 3, m)] = v.w;
      uint4 u;
      u.x = cvt2h(v.x, v.x); u.y = cvt2h(v.y, v.y);
      u.z = cvt2h(v.z, v.z); u.w = cvt2h(v.w, v.w);
      *(uint4*)&XT_u[(m << 7) + nb] = u;
    }
    if (tid < 768) {   // zero-pad h = 40..63 (L0's P = X)
      int n = tid / 6, hg = 40 + (tid - n * 6) * 4;
      *(float4*)&XP_s[xp_idx(n, hg)] = make_float4(0.f, 0.f, 0.f, 0.f);
    }
  }
  __syncthreads();

  const int hq = ki * 16 + hi * 8;   // lane's layer-constant h-octet base
  float sacc[4] = {0.f, 0.f, 0.f, 0.f};
  const float* biasL[3] = {bias0, bias1, bias2};

  for (int lidx = 0; lidx < 3; ++lidx) {
    const unsigned short* W = Wp + (size_t)lidx * 327680;
    const float* bias = biasL[lidx];

    f32x16 acc[4];
#pragma unroll
    for (int f = 0; f < 4; ++f)
#pragma unroll
      for (int e = 0; e < 16; ++e) acc[f][e] = 0.f;

    if (!(lidx == 0 && ki == 3)) {   // ki=3 is pure zero-pad for L0
      // P register cache: packed fp16 octet per fn col, layer-constant
      uint4 Pc[4];
#pragma unroll
      for (int fn = 0; fn < 4; ++fn) {
        const int col = fn * 32 + l31;
        const int rb = col << 6, sw = (col & 15) << 2;
        f32x4 pa = *(const f32x4*)&XP_s[rb + (hq ^ sw)];
        f32x4 pb = *(const f32x4*)&XP_s[rb + ((hq + 4) ^ sw)];
        Pc[fn].x = cvt2h(pa[0], pa[1]); Pc[fn].y = cvt2h(pa[2], pa[3]);
        Pc[fn].z = cvt2h(pb[0], pb[1]); Pc[fn].w = cvt2h(pb[2], pb[3]);
      }
      // fragment stream: slice s = 4t + ki, per-t stride = 4*512 = 2048 halves
      const unsigned short* wp = W + (((size_t)(oq * 160 + ki)) << 9) + (lane << 3);
      uint4 Aa = *(const uint4*)wp;
      uint4 Ab;
      for (int t = 0; t < 40; t += 2) {
        Ab = *(const uint4*)(wp + (t + 1) * 2048);
#pragma unroll
        for (int fn = 0; fn < 4; ++fn) {
          unsigned xu = XT_u[(t << 7) + fn * 32 + l31];
          uint4 Bu;
          asm("v_pk_mul_f16 %0, %1, %2" : "=v"(Bu.x) : "v"(Pc[fn].x), "v"(xu));
          asm("v_pk_mul_f16 %0, %1, %2" : "=v"(Bu.y) : "v"(Pc[fn].y), "v"(xu));
          asm("v_pk_mul_f16 %0, %1, %2" : "=v"(Bu.z) : "v"(Pc[fn].z), "v"(xu));
          asm("v_pk_mul_f16 %0, %1, %2" : "=v"(Bu.w) : "v"(Pc[fn].w), "v"(xu));
          acc[fn] = MFMA(Aa, Bu, acc[fn]);
        }
        Aa = *(const uint4*)(wp + ((t + 2 < 40) ? (t + 2) : 0) * 2048);
#pragma unroll
        for (int fn = 0; fn < 4; ++fn) {
          unsigned xu = XT_u[((t + 1) << 7) + fn * 32 + l31];
          uint4 Bu;
          asm("v_pk_mul_f16 %0, %1, %2" : "=v"(Bu.x) : "v"(Pc[fn].x), "v"(xu));
          asm("v_pk_mul_f16 %0, %1, %2" : "=v"(Bu.y) : "v"(Pc[fn].y), "v"(xu));
          asm("v_pk_mul_f16 %0, %1, %2" : "=v"(Bu.z) : "v"(Pc[fn].z), "v"(xu));
          asm("v_pk_mul_f16 %0, %1, %2" : "=v"(Bu.w) : "v"(Pc[fn].w), "v"(xu));
          acc[fn] = MFMA(Ab, Bu, acc[fn]);
        }
      }
    }

    // ---- k-reduction tree. Round 1: ki{2,3} -> ki{0,1}, two f-pair sub-rounds.
    __syncthreads();
#pragma unroll
    for (int fp = 0; fp < 2; ++fp) {
      if (ki >= 2) {
        const int base = ((oq << 1) | (ki - 2)) << 11;
#pragma unroll
        for (int fl = 0; fl < 2; ++fl)
#pragma unroll
          for (int qd = 0; qd < 4; ++qd) {
            const int f = fp * 2 + fl;
            f32x4 v = {acc[f][qd*4+0], acc[f][qd*4+1], acc[f][qd*4+2], acc[f][qd*4+3]};
            *(f32x4*)&scr_s[base + ((fl << 2) | qd) * 256 + (lane << 2)] = v;
          }
      }
      __syncthreads();
      if (ki < 2) {
        const int base = ((oq << 1) | ki) << 11;
#pragma unroll
        for (int fl = 0; fl < 2; ++fl)
#pragma unroll
          for (int qd = 0; qd < 4; ++qd) {
            const int f = fp * 2 + fl;
            f32x4 v = *(const f32x4*)&scr_s[base + ((fl << 2) | qd) * 256 + (lane << 2)];
#pragma unroll
            for (int r = 0; r < 4; ++r) acc[f][qd * 4 + r] += v[r];
          }
      }
      __syncthreads();
    }
    // Round 2: ki1 -> ki0, all 4 f at once (4 slots x 16KB = 64KB)
    if (ki == 1) {
      const int base = oq << 12;
#pragma unroll
      for (int f = 0; f < 4; ++f)
#pragma unroll
        for (int qd = 0; qd < 4; ++qd) {
          f32x4 v = {acc[f][qd*4+0], acc[f][qd*4+1], acc[f][qd*4+2], acc[f][qd*4+3]};
          *(f32x4*)&scr_s[base + ((f << 2) | qd) * 256 + (lane << 2)] = v;
        }
    }
    __syncthreads();
    if (ki == 0) {
      const int base = oq << 12;
#pragma unroll
      for (int f = 0; f < 4; ++f)
#pragma unroll
        for (int qd = 0; qd < 4; ++qd) {
          f32x4 v = *(const f32x4*)&scr_s[base + ((f << 2) | qd) * 256 + (lane << 2)];
#pragma unroll
          for (int r = 0; r < 4; ++r) acc[f][qd * 4 + r] += v[r];
        }
      if (oq < 2) {          // P half: o = 0..63 -> next layer's P
        if (lidx < 2) {
#pragma unroll
          for (int fn = 0; fn < 4; ++fn) {
            const int col = fn * 32 + l31;
            const int rb = col << 6, sw = (col & 15) << 2;
#pragma unroll
            for (int qd = 0; qd < 4; ++qd) {
              const int o0 = oq * 32 + qd * 8 + hi * 4;
              float4 bv = *(const float4*)&bias[o0];
              f32x4 r;
              r[0] = fmaxf(acc[fn][qd*4+0] + bv.x, 0.f);
              r[1] = fmaxf(acc[fn][qd*4+1] + bv.y, 0.f);
              r[2] = fmaxf(acc[fn][qd*4+2] + bv.z, 0.f);
              r[3] = fmaxf(acc[fn][qd*4+3] + bv.w, 0.f);
              *(f32x4*)&XP_s[rb + (o0 ^ sw)] = r;
            }
          }
        }
      } else {               // direct half: o = 64..127 -> fold with wl
#pragma unroll
        for (int fn = 0; fn < 4; ++fn)
#pragma unroll
          for (int qd = 0; qd < 4; ++qd) {
            const int o0 = 64 + (oq - 2) * 32 + qd * 8 + hi * 4;
            float4 bv = *(const float4*)&bias[o0];
            float4 wv4 = *(const float4*)&wl_s[lidx * 64 + (o0 - 64)];
            sacc[fn] += fmaxf(acc[fn][qd*4+0] + bv.x, 0.f) * wv4.x
                      + fmaxf(acc[fn][qd*4+1] + bv.y, 0.f) * wv4.y
                      + fmaxf(acc[fn][qd*4+2] + bv.z, 0.f) * wv4.z
                      + fmaxf(acc[fn][qd*4+3] + bv.w, 0.f) * wv4.w;
          }
      }
    }
    __syncthreads();   // new P visible before next layer's Pc load
  }

  // ---- head: direct partials live in (ki==0, oq>=2); cols n = f*32 + l31
#pragma unroll
  for (int f = 0; f < 4; ++f) {
    float v = sacc[f] + __shfl_xor(sacc[f], 32);
    if (ki == 0 && oq >= 2 && lane < 32) atomicAdd(&s_s[f * 32 + l31], v);
  }
  __syncthreads();
  if (tid < 8) {
    float s = 0.f;
#pragma unroll
    for (int d = 0; d < 16; ++d) s += s_s[tid * 16 + d];
    out[bid * 8 + tid] = s;
  }
}

extern "C" void kernel_launch(void* const* d_in, const int* in_sizes, int n_in,
                              void* d_out, int out_size, void* d_ws, size_t ws_size,
                              hipStream_t stream) {
  const float* x  = (const float*)d_in[0];
  const float* w0 = (const float*)d_in[1];
  const float* b0 = (const float*)d_in[2];
  const float* w1 = (const float*)d_in[3];
  const float* b1 = (const float*)d_in[4];
  const float* w2 = (const float*)d_in[5];
  const float* b2 = (const float*)d_in[6];
  const float* wl = (const float*)d_in[7];
  unsigned short* Wp = (unsigned short*)d_ws;  // 983040 fp16 = 1.92 MB

  permute_w_kernel<<<384, 256, 0, stream>>>(w0, w1, w2, Wp);
  cin_kernel<<<256, 1024, 0, stream>>>(x, Wp, b0, b1, b2, wl, (float*)d_out);
}

// Round 11
// 132.967 us; speedup vs baseline: 2.1814x; 1.0306x over previous
//
#include <hip/hip_runtime.h>
#include <hip/hip_bf16.h>

typedef _Float16 f16x8 __attribute__((ext_vector_type(8)));
typedef float f32x4   __attribute__((ext_vector_type(4)));
typedef float f32x16  __attribute__((ext_vector_type(16)));

__device__ __forceinline__ unsigned cvt2h(float a, float b) {
  auto h = __builtin_amdgcn_cvt_pkrtz(a, b);   // __fp16 ext_vector(2)
  unsigned u; __builtin_memcpy(&u, &h, 4); return u;
}

__device__ __forceinline__ f32x16 MFMA(uint4 a, uint4 b, f32x16 c) {
  return __builtin_amdgcn_mfma_f32_32x32x16_f16(
      __builtin_bit_cast(f16x8, a), __builtin_bit_cast(f16x8, b), c, 0, 0, 0);
}

// XP: [128 cols][64 h] f32, XOR swizzle at 4-word (16B) granule keyed on n&15
__device__ __forceinline__ int xp_idx(int n, int h) { return (n << 6) + (h ^ ((n & 15) << 2)); }

// ---- weight permute + fp16 cast into FRAGMENT-MAJOR layout ----
// Logical W'[o][k'], k' = m*64 + h (L0 zero-padded h>=40).
// Physical: W''[(ot*160 + s)*64 + fl]*8 + e, fl = (o&31) + ((k&15)>>3)*32
// -> one 32x32x16 A-fragment = contiguous 1KB per wave.
__global__ __launch_bounds__(256) void permute_w_kernel(
    const float* __restrict__ w0, const float* __restrict__ w1,
    const float* __restrict__ w2, unsigned short* __restrict__ Wp) {
  __shared__ float rowt[40 * 65];   // [m][h], padded stride 65
  const int b = blockIdx.x;
  const float* src; unsigned short* dst; int Kin, L0, o;
  if (b < 128)      { o = b;       src = w0 + o * 1600; dst = Wp;          Kin = 1600; L0 = 1; }
  else if (b < 256) { o = b - 128; src = w1 + o * 2560; dst = Wp + 327680; Kin = 2560; L0 = 0; }
  else              { o = b - 256; src = w2 + o * 2560; dst = Wp + 655360; Kin = 2560; L0 = 0; }
  for (int i = threadIdx.x; i < (Kin >> 2); i += 256) {
    float4 v = ((const float4*)src)[i];
    int f = i << 2;
    int h = f / 40, m = f - h * 40;   // src h-major, m inner; 4 | 40 so no straddle
    rowt[(m + 0) * 65 + h] = v.x;
    rowt[(m + 1) * 65 + h] = v.y;
    rowt[(m + 2) * 65 + h] = v.z;
    rowt[(m + 3) * 65 + h] = v.w;
  }
  __syncthreads();
  const int ot = o >> 5, lanelo = o & 31;
  for (int i = threadIdx.x; i < 320; i += 256) {   // k-octets
    const int k = i << 3;
    const int m = k >> 6, h = k & 63;
    const int s = k >> 4, hi2 = (k >> 3) & 1;
    uint4 u;
    if (L0 && h >= 40) {
      u = make_uint4(0u, 0u, 0u, 0u);
    } else {
      const float* p = &rowt[m * 65 + h];
      u.x = cvt2h(p[0], p[1]); u.y = cvt2h(p[2], p[3]);
      u.z = cvt2h(p[4], p[5]); u.w = cvt2h(p[6], p[7]);
    }
    *(uint4*)&dst[(((size_t)ot * 160 + s) * 64 + lanelo + hi2 * 32) * 8] = u;
  }
}

// ---- fused CIN: 128 cols/block, 8 waves = 2 oh x 4 ki ----
// 32x32x16 f16 MFMA; wave: mr=2 (o=64), fn=4 (128 cols), slices s == ki (mod 4).
// 2 waves/SIMD with 256-reg budget: acc 128 + working set ~70 -> NO spill.
__global__ __launch_bounds__(512, 2) void cin_kernel(
    const float* __restrict__ x, const unsigned short* __restrict__ Wp,
    const float* __restrict__ bias0, const float* __restrict__ bias1,
    const float* __restrict__ bias2, const float* __restrict__ wl,
    float* __restrict__ out) {
  __shared__ __align__(16) float XP_s[128 * 64];     // 32KB: X-padded (L0) then P
  __shared__ __align__(16) unsigned XT_u[40 * 128];  // 20KB: x as dup'd fp16 pairs [m][col]
  __shared__ __align__(16) float scr_s[16384];       // 64KB: k-reduction scratch
  __shared__ float wl_s[192];
  __shared__ float s_s[128];

  const int tid = threadIdx.x;
  const int lane = tid & 63;
  const int wv = tid >> 6;        // 0..7
  const int bid = blockIdx.x;
  const int l31 = lane & 31;
  const int hi = lane >> 5;
  const int ki = wv & 3;          // k-stripe (s mod 4)
  const int oh = wv >> 2;         // o-half (64 rows)

  if (tid < 192) wl_s[tid] = wl[tid];

  {  // stage x: 8 b's, global layout (b_l, m, d)
    const float4* xg = (const float4*)(x + (size_t)bid * 5120);
    for (int i = tid; i < 1280; i += 512) {
      float4 v = xg[i];
      int d4 = (i & 3) << 2;
      int m = (i >> 2) % 40;
      int b_l = i / 160;
      int nb = b_l * 16 + d4;
      XP_s[xp_idx(nb + 0, m)] = v.x;
      XP_s[xp_idx(nb + 1, m)] = v.y;
      XP_s[xp_idx(nb + 2, m)] = v.z;
      XP_s[xp_idx(nb + 3, m)] = v.w;
      uint4 u;
      u.x = cvt2h(v.x, v.x); u.y = cvt2h(v.y, v.y);
      u.z = cvt2h(v.z, v.z); u.w = cvt2h(v.w, v.w);
      *(uint4*)&XT_u[(m << 7) + nb] = u;
    }
    for (int i = tid; i < 768; i += 512) {   // zero-pad h = 40..63 (L0's P = X)
      int n = i / 6, hg = 40 + (i - n * 6) * 4;
      *(float4*)&XP_s[xp_idx(n, hg)] = make_float4(0.f, 0.f, 0.f, 0.f);
    }
  }
  __syncthreads();

  const int hq = ki * 16 + hi * 8;   // lane's layer-constant h-octet base
  float sacc[4] = {0.f, 0.f, 0.f, 0.f};
  const float* biasL[3] = {bias0, bias1, bias2};

  for (int lidx = 0; lidx < 3; ++lidx) {
    const unsigned short* W = Wp + (size_t)lidx * 327680;
    const float* bias = biasL[lidx];

    f32x16 acc[2][4];
#pragma unroll
    for (int mr = 0; mr < 2; ++mr)
#pragma unroll
      for (int f = 0; f < 4; ++f)
#pragma unroll
        for (int e = 0; e < 16; ++e) acc[mr][f][e] = 0.f;

    if (!(lidx == 0 && ki == 3)) {   // ki=3 is pure zero-pad for L0
      // P register cache: packed fp16 octet per fn col, layer-constant
      uint4 Pc[4];
#pragma unroll
      for (int fn = 0; fn < 4; ++fn) {
        const int col = fn * 32 + l31;
        const int rb = col << 6, sw = (col & 15) << 2;
        f32x4 pa = *(const f32x4*)&XP_s[rb + (hq ^ sw)];
        f32x4 pb = *(const f32x4*)&XP_s[rb + ((hq + 4) ^ sw)];
        Pc[fn].x = cvt2h(pa[0], pa[1]); Pc[fn].y = cvt2h(pa[2], pa[3]);
        Pc[fn].z = cvt2h(pb[0], pb[1]); Pc[fn].w = cvt2h(pb[2], pb[3]);
      }
      // two fragment streams (mr=0,1): slice s = 4t + ki, per-t stride 2048 halves
      const unsigned short* wp0 = W + (((size_t)((oh * 2 + 0) * 160 + ki)) << 9) + (lane << 3);
      const unsigned short* wp1 = W + (((size_t)((oh * 2 + 1) * 160 + ki)) << 9) + (lane << 3);
      auto ldf = [&](const unsigned short* p, int t) -> uint4 {
        return *(const uint4*)(p + (t < 40 ? t : 0) * 2048);
      };
      uint4 Aa0 = ldf(wp0, 0), Aa1 = ldf(wp1, 0);
      uint4 Ab0 = ldf(wp0, 1), Ab1 = ldf(wp1, 1);
#pragma unroll
      for (int t = 0; t < 40; t += 2) {
        uint4 Ac0 = ldf(wp0, t + 2), Ac1 = ldf(wp1, t + 2);
#pragma unroll
        for (int fn = 0; fn < 4; ++fn) {
          unsigned xu = XT_u[(t << 7) + fn * 32 + l31];
          uint4 Bu;
          asm("v_pk_mul_f16 %0, %1, %2" : "=v"(Bu.x) : "v"(Pc[fn].x), "v"(xu));
          asm("v_pk_mul_f16 %0, %1, %2" : "=v"(Bu.y) : "v"(Pc[fn].y), "v"(xu));
          asm("v_pk_mul_f16 %0, %1, %2" : "=v"(Bu.z) : "v"(Pc[fn].z), "v"(xu));
          asm("v_pk_mul_f16 %0, %1, %2" : "=v"(Bu.w) : "v"(Pc[fn].w), "v"(xu));
          acc[0][fn] = MFMA(Aa0, Bu, acc[0][fn]);
          acc[1][fn] = MFMA(Aa1, Bu, acc[1][fn]);
        }
        uint4 Ad0 = ldf(wp0, t + 3), Ad1 = ldf(wp1, t + 3);
#pragma unroll
        for (int fn = 0; fn < 4; ++fn) {
          unsigned xu = XT_u[((t + 1) << 7) + fn * 32 + l31];
          uint4 Bu;
          asm("v_pk_mul_f16 %0, %1, %2" : "=v"(Bu.x) : "v"(Pc[fn].x), "v"(xu));
          asm("v_pk_mul_f16 %0, %1, %2" : "=v"(Bu.y) : "v"(Pc[fn].y), "v"(xu));
          asm("v_pk_mul_f16 %0, %1, %2" : "=v"(Bu.z) : "v"(Pc[fn].z), "v"(xu));
          asm("v_pk_mul_f16 %0, %1, %2" : "=v"(Bu.w) : "v"(Pc[fn].w), "v"(xu));
          acc[0][fn] = MFMA(Ab0, Bu, acc[0][fn]);
          acc[1][fn] = MFMA(Ab1, Bu, acc[1][fn]);
        }
        Aa0 = Ac0; Aa1 = Ac1; Ab0 = Ad0; Ab1 = Ad1;
      }
    }

    // ---- k-reduction tree. Round 1: ki{2,3} -> ki{0,1}, one sub-round per mr.
    __syncthreads();
#pragma unroll
    for (int mr = 0; mr < 2; ++mr) {
      if (ki >= 2) {
        const int base = ((oh << 1) | (ki - 2)) << 12;   // 4 slots x 16KB
#pragma unroll
        for (int f = 0; f < 4; ++f)
#pragma unroll
          for (int qd = 0; qd < 4; ++qd) {
            f32x4 v = {acc[mr][f][qd*4+0], acc[mr][f][qd*4+1], acc[mr][f][qd*4+2], acc[mr][f][qd*4+3]};
            *(f32x4*)&scr_s[base + ((f << 2) | qd) * 256 + (lane << 2)] = v;
          }
      }
      __syncthreads();
      if (ki < 2) {
        const int base = ((oh << 1) | ki) << 12;
#pragma unroll
        for (int f = 0; f < 4; ++f)
#pragma unroll
          for (int qd = 0; qd < 4; ++qd) {
            f32x4 v = *(const f32x4*)&scr_s[base + ((f << 2) | qd) * 256 + (lane << 2)];
#pragma unroll
            for (int r = 0; r < 4; ++r) acc[mr][f][qd * 4 + r] += v[r];
          }
      }
      __syncthreads();
    }
    // Round 2: ki1 -> ki0, full acc (2 slots x 32KB)
    if (ki == 1) {
      const int base = oh << 13;
#pragma unroll
      for (int mr = 0; mr < 2; ++mr)
#pragma unroll
        for (int f = 0; f < 4; ++f)
#pragma unroll
          for (int qd = 0; qd < 4; ++qd) {
            f32x4 v = {acc[mr][f][qd*4+0], acc[mr][f][qd*4+1], acc[mr][f][qd*4+2], acc[mr][f][qd*4+3]};
            *(f32x4*)&scr_s[base + (((mr << 2) | f) << 2 | qd) * 256 + (lane << 2)] = v;
          }
    }
    __syncthreads();
    if (ki == 0) {
      const int base = oh << 13;
#pragma unroll
      for (int mr = 0; mr < 2; ++mr)
#pragma unroll
        for (int f = 0; f < 4; ++f)
#pragma unroll
          for (int qd = 0; qd < 4; ++qd) {
            f32x4 v = *(const f32x4*)&scr_s[base + (((mr << 2) | f) << 2 | qd) * 256 + (lane << 2)];
#pragma unroll
            for (int r = 0; r < 4; ++r) acc[mr][f][qd * 4 + r] += v[r];
          }
      if (oh == 0) {         // P half: o = 0..63 -> next layer's P
        if (lidx < 2) {
#pragma unroll
          for (int mr = 0; mr < 2; ++mr)
#pragma unroll
            for (int fn = 0; fn < 4; ++fn) {
              const int col = fn * 32 + l31;
              const int rb = col << 6, sw = (col & 15) << 2;
#pragma unroll
              for (int qd = 0; qd < 4; ++qd) {
                const int o0 = mr * 32 + qd * 8 + hi * 4;
                float4 bv = *(const float4*)&bias[o0];
                f32x4 r;
                r[0] = fmaxf(acc[mr][fn][qd*4+0] + bv.x, 0.f);
                r[1] = fmaxf(acc[mr][fn][qd*4+1] + bv.y, 0.f);
                r[2] = fmaxf(acc[mr][fn][qd*4+2] + bv.z, 0.f);
                r[3] = fmaxf(acc[mr][fn][qd*4+3] + bv.w, 0.f);
                *(f32x4*)&XP_s[rb + (o0 ^ sw)] = r;
              }
            }
        }
      } else {               // direct half: o = 64..127 -> fold with wl
#pragma unroll
        for (int mr = 0; mr < 2; ++mr)
#pragma unroll
          for (int fn = 0; fn < 4; ++fn)
#pragma unroll
            for (int qd = 0; qd < 4; ++qd) {
              const int o0 = 64 + mr * 32 + qd * 8 + hi * 4;
              float4 bv = *(const float4*)&bias[o0];
              float4 wv4 = *(const float4*)&wl_s[lidx * 64 + (o0 - 64)];
              sacc[fn] += fmaxf(acc[mr][fn][qd*4+0] + bv.x, 0.f) * wv4.x
                        + fmaxf(acc[mr][fn][qd*4+1] + bv.y, 0.f) * wv4.y
                        + fmaxf(acc[mr][fn][qd*4+2] + bv.z, 0.f) * wv4.z
                        + fmaxf(acc[mr][fn][qd*4+3] + bv.w, 0.f) * wv4.w;
            }
      }
    }
    __syncthreads();   // new P visible before next layer's Pc load
  }

  // ---- head: direct partials live in the single (ki==0, oh==1) wave
#pragma unroll
  for (int f = 0; f < 4; ++f) {
    float v = sacc[f] + __shfl_xor(sacc[f], 32);
    if (ki == 0 && oh == 1 && lane < 32) s_s[f * 32 + l31] = v;
  }
  __syncthreads();
  if (tid < 8) {
    float s = 0.f;
#pragma unroll
    for (int d = 0; d < 16; ++d) s += s_s[tid * 16 + d];
    out[bid * 8 + tid] = s;
  }
}

extern "C" void kernel_launch(void* const* d_in, const int* in_sizes, int n_in,
                              void* d_out, int out_size, void* d_ws, size_t ws_size,
                              hipStream_t stream) {
  const float* x  = (const float*)d_in[0];
  const float* w0 = (const float*)d_in[1];
  const float* b0 = (const float*)d_in[2];
  const float* w1 = (const float*)d_in[3];
  const float* b1 = (const float*)d_in[4];
  const float* w2 = (const float*)d_in[5];
  const float* b2 = (const float*)d_in[6];
  const float* wl = (const float*)d_in[7];
  unsigned short* Wp = (unsigned short*)d_ws;  // 983040 fp16 = 1.92 MB

  permute_w_kernel<<<384, 256, 0, stream>>>(w0, w1, w2, Wp);
  cin_kernel<<<256, 512, 0, stream>>>(x, Wp, b0, b1, b2, wl, (float*)d_out);
}